// Round 9
// baseline (115.949 us; speedup 1.0000x reference)
//
#include <hip/hip_runtime.h>
#include <hip/hip_bf16.h>
#include <math.h>

// Problem constants
#define B_SZ   1024
#define F_SZ   1024
#define NKER   100
#define DKER   5
#define CCOLS  (NKER * DKER)   // 500
#define OUTW   (F_SZ + NKER)   // 1124
#define LOG2E_F 1.44269504088896340736f

typedef __attribute__((ext_vector_type(8))) short bf16x8;
typedef __attribute__((ext_vector_type(4))) float f32x4;

// single-instruction hardware exp2 (FTZ below 2^-126 is fine: negligible terms)
__device__ __forceinline__ float exp2_hw(float x) {
    float r;
    asm("v_exp_f32 %0, %1" : "=v"(r) : "v"(x));
    return r;
}
// pack 2 f32 -> 2 bf16 (RNE) in one instruction
__device__ __forceinline__ unsigned cvt_pk_bf16(float lo, float hi) {
    unsigned r;
    asm("v_cvt_pk_bf16_f32 %0, %1, %2" : "=v"(r) : "v"(lo), "v"(hi));
    return r;
}

// ---------------------------------------------------------------------------
// Kernel 1: copy x into out[:, :1024]. Feat region fully written by pair,
// mt fully written by gemm (plain stores) -> no zeroing anywhere.
// ---------------------------------------------------------------------------
__global__ __launch_bounds__(256) void init_kernel(const float* __restrict__ x,
                                                   float* __restrict__ out) {
    const int row = blockIdx.x;
    const int t = threadIdx.x;
    const float4 v = *reinterpret_cast<const float4*>(&x[row * F_SZ + t * 4]);
    *reinterpret_cast<float4*>(&out[row * OUTW + t * 4]) = v;
}

// ---------------------------------------------------------------------------
// Kernel 2a: stage x -> xb in FRAGMENT-MAJOR bf16 layout:
//   xb[(jt*32+s)*512 + l*8 + e] = bf16(x[jt*16 + (l&15)][s*32 + (l>>4)*8 + e])
// so the gemm's B-frag load is ONE coalesced dwordx4 per wave-step.
// ---------------------------------------------------------------------------
__global__ __launch_bounds__(256) void stage_xb_kernel(const float* __restrict__ x,
                                                       short* __restrict__ xb) {
    const int tid = blockIdx.x * 256 + threadIdx.x;   // 0..131071
    const int l = tid & 63;
    const int g = tid >> 6;            // jt*32 + s, 0..2047
    const int jt = g >> 5, s = g & 31;
    const int j = jt * 16 + (l & 15);
    const int kb = s * 32 + (l >> 4) * 8;
    const float4 v0 = *reinterpret_cast<const float4*>(&x[j * F_SZ + kb]);
    const float4 v1 = *reinterpret_cast<const float4*>(&x[j * F_SZ + kb + 4]);
    uint4 w;
    w.x = cvt_pk_bf16(v0.x, v0.y);
    w.y = cvt_pk_bf16(v0.z, v0.w);
    w.z = cvt_pk_bf16(v1.x, v1.y);
    w.w = cvt_pk_bf16(v1.z, v1.w);
    *reinterpret_cast<uint4*>(&xb[(size_t)g * 512 + l * 8]) = w;
}

// ---------------------------------------------------------------------------
// Kernel 2b: BARRIER-FREE bf16 MFMA GEMM (no LDS, no syncthreads, no atomics):
//   mt[c][j] = LOG2E * sum_f x[j][f] * T[f][c]
// Each wave owns a 16c x 16j tile; B-frag = 1 coalesced dwordx4 from xb;
// A-frag = 8 dword loads from T (lanes 0..15 consecutive c -> full 64B segs),
// cvt_pk in-reg. 32 K-steps, compiler free to keep loads in flight (no
// vmcnt(0) barrier drain - r2..r8 LDS gemms all paid that, ~45us each).
// Frag layout verified r4-r8 (absmax 7.8e-3): A/B lane l = row/col l&15,
// kchunk (l>>4)*8; C/D col=l&15 (j), row=(l>>4)*4+q (c).
// ---------------------------------------------------------------------------
__global__ __launch_bounds__(256) void gemm_frag_kernel(const float* __restrict__ T,
                                                        const short* __restrict__ xb,
                                                        float* __restrict__ mt) {
    const int tid = threadIdx.x;
    const int l = tid & 63;
    const int w = tid >> 6;
    const int tile = blockIdx.x * 4 + w;   // 0..2047 = jt*32 + ct
    const int ct = tile & 31, jt = tile >> 5;
    const int lr = l & 15;
    const int lk = (l >> 4) * 8;
    const int cA = ct * 16 + lr;
    const int cL = (cA < CCOLS) ? cA : (CCOLS - 1);   // clamp; store-guarded

    const float* ap = T + (size_t)lk * CCOLS + cL;
    const short* bp = xb + ((size_t)(jt * 32) * 512 + l * 8);

    f32x4 acc = {0.f, 0.f, 0.f, 0.f};
    #pragma unroll 4
    for (int s = 0; s < 32; ++s) {
        const float a0 = ap[0 * CCOLS], a1 = ap[1 * CCOLS];
        const float a2 = ap[2 * CCOLS], a3 = ap[3 * CCOLS];
        const float a4 = ap[4 * CCOLS], a5 = ap[5 * CCOLS];
        const float a6 = ap[6 * CCOLS], a7 = ap[7 * CCOLS];
        const bf16x8 bf = *reinterpret_cast<const bf16x8*>(bp);
        ap += 32 * CCOLS;
        bp += 512;
        union { unsigned u[4]; bf16x8 v; } A;
        A.u[0] = cvt_pk_bf16(a0, a1);
        A.u[1] = cvt_pk_bf16(a2, a3);
        A.u[2] = cvt_pk_bf16(a4, a5);
        A.u[3] = cvt_pk_bf16(a6, a7);
        acc = __builtin_amdgcn_mfma_f32_16x16x32_bf16(A.v, bf, acc, 0, 0, 0);
    }

    const int jst = jt * 16 + lr;
    const int cst = ct * 16 + (l >> 4) * 4;
    #pragma unroll
    for (int q = 0; q < 4; ++q) {
        const int c = cst + q;
        if (c < CCOLS) mt[c * B_SZ + jst] = acc[q] * LOG2E_F;
    }
}

// ---------------------------------------------------------------------------
// Kernel 2-fallback (ws < 4MB): r8's in-block split-K gemm (verified).
// ---------------------------------------------------------------------------
#define GAPAD 40

__global__ __launch_bounds__(512) void gemm_block_kernel(const float* __restrict__ x,
                                                         const float* __restrict__ T,
                                                         float* __restrict__ mt) {
    __shared__ short Al[2][32][GAPAD];
    __shared__ short Bl[2][32][GAPAD];
    __shared__ float red[4][64][4];
    const int tid = threadIdx.x;
    const int l = tid & 63;
    const int w = tid >> 6;
    const int h = tid >> 8;
    const int ht = tid & 255;
    const int c0 = blockIdx.x * 32;
    const int j0 = blockIdx.y * 32;
    const int fh = h * (F_SZ / 2);

    const int sac = ht & 31;
    const int sak = (ht >> 5) * 4;
    const int cldA = (c0 + sac < CCOLS) ? (c0 + sac) : (CCOLS - 1);
    const int sbj = ht >> 3;
    const int sbk = (ht & 7) * 4;

    const int q = w & 3;
    const int cq = (q & 1) * 16;
    const int jq = (q >> 1) * 16;
    const int fr = (l >> 4) * 8;
    const int ar = cq + (l & 15);
    const int br = jq + (l & 15);

    f32x4 acc = {0.f, 0.f, 0.f, 0.f};

    for (int s = 0; s < 16; ++s) {
        const int fb = fh + s * 32;
        const float a0 = T[(fb + sak + 0) * CCOLS + cldA];
        const float a1 = T[(fb + sak + 1) * CCOLS + cldA];
        const float a2 = T[(fb + sak + 2) * CCOLS + cldA];
        const float a3 = T[(fb + sak + 3) * CCOLS + cldA];
        const float4 b = *reinterpret_cast<const float4*>(&x[(j0 + sbj) * F_SZ + fb + sbk]);
        if (s) __syncthreads();
        {
            uint2 aw; aw.x = cvt_pk_bf16(a0, a1); aw.y = cvt_pk_bf16(a2, a3);
            *reinterpret_cast<uint2*>(&Al[h][sac][sak]) = aw;
            uint2 bw; bw.x = cvt_pk_bf16(b.x, b.y); bw.y = cvt_pk_bf16(b.z, b.w);
            *reinterpret_cast<uint2*>(&Bl[h][sbj][sbk]) = bw;
        }
        __syncthreads();
        const bf16x8 af = *reinterpret_cast<const bf16x8*>(&Al[h][ar][fr]);
        const bf16x8 bf = *reinterpret_cast<const bf16x8*>(&Bl[h][br][fr]);
        acc = __builtin_amdgcn_mfma_f32_16x16x32_bf16(af, bf, acc, 0, 0, 0);
    }

    if (h == 1) {
        #pragma unroll
        for (int qq = 0; qq < 4; ++qq) red[q][l][qq] = acc[qq];
    }
    __syncthreads();
    if (h == 0) {
        const int jst = j0 + jq + (l & 15);
        const int cst = c0 + cq + (l >> 4) * 4;
        #pragma unroll
        for (int qq = 0; qq < 4; ++qq) {
            const int c = cst + qq;
            if (c < CCOLS)
                mt[c * B_SZ + jst] = (acc[qq] + red[q][l][qq]) * LOG2E_F;
        }
    }
}

// ---------------------------------------------------------------------------
// Kernel 3: pairwise exp-L1. The j-stream is WAVE-UNIFORM -> moved to the
// SCALAR pipe: 5x s_load_dwordx4 per 4 j (SGPR q-values, VOP2 sub takes one
// SGPR src). Zero LDS in the inner loop (r8 was LDS-issue-bound: 2.05M
// ds_read_b128 = ~40us of LDS pipe). Grid (16,100) x 4 waves = 25 waves/CU.
// Wave w sweeps j-quarter w; 1KB-LDS cross-wave reduce; 1 store per (i,k).
// mt is LOG2E-pre-scaled.
// ---------------------------------------------------------------------------
__global__ __launch_bounds__(256) void pair_kernel(const float* __restrict__ mt,
                                                   float* __restrict__ out) {
    __shared__ float red[256];
    const int tid = threadIdx.x;
    const int bx = blockIdx.x;          // i-chunk (64 i's)
    const int k = blockIdx.y;
    const int cb = k * DKER;
    const int lane = tid & 63;
    const int wu = __builtin_amdgcn_readfirstlane(tid >> 6);   // SGPR wave id
    const int i = bx * 64 + lane;

    // own i-point (coalesced per-lane loads)
    const float a0 = mt[(cb + 0) * B_SZ + i];
    const float a1 = mt[(cb + 1) * B_SZ + i];
    const float a2 = mt[(cb + 2) * B_SZ + i];
    const float a3 = mt[(cb + 3) * B_SZ + i];
    const float a4 = mt[(cb + 4) * B_SZ + i];

    // scalar base for this wave's j-quarter (plane stride = 4096B = 0x1000)
    unsigned long long base =
        (unsigned long long)(uintptr_t)(mt + (size_t)cb * B_SZ + wu * 256);

    float acc = 0.f;
    for (int jb = 0; jb < 64; ++jb) {
        f32x4 q0, q1, q2, q3, q4;
        asm("s_load_dwordx4 %0, %[p], 0x0\n\t"
            "s_load_dwordx4 %1, %[p], 0x1000\n\t"
            "s_load_dwordx4 %2, %[p], 0x2000\n\t"
            "s_load_dwordx4 %3, %[p], 0x3000\n\t"
            "s_load_dwordx4 %4, %[p], 0x4000\n\t"
            "s_waitcnt lgkmcnt(0)"
            : "=s"(q0), "=s"(q1), "=s"(q2), "=s"(q3), "=s"(q4)
            : [p] "s"(base));
#define DOJ(E) { \
        const float d0 = q0[E] - a0; \
        const float d1 = q1[E] - a1; \
        const float d2 = q2[E] - a2; \
        const float d3 = q3[E] - a3; \
        const float d4 = q4[E] - a4; \
        const float p01 = fabsf(d0) + fabsf(d1); \
        const float p23 = fabsf(d2) + fabsf(d3); \
        const float p234 = p23 + fabsf(d4); \
        acc += exp2_hw(-p01 - p234); }
        DOJ(0) DOJ(1) DOJ(2) DOJ(3)
#undef DOJ
        base += 16;   // 4 j's * 4B
    }

    red[tid] = acc;
    __syncthreads();
    if (tid < 64) {
        const float s = red[tid] + red[tid + 64] + red[tid + 128] + red[tid + 192];
        out[(bx * 64 + tid) * OUTW + F_SZ + k] = s;
    }
}

// ---------------------------------------------------------------------------
extern "C" void kernel_launch(void* const* d_in, const int* in_sizes, int n_in,
                              void* d_out, int out_size, void* d_ws, size_t ws_size,
                              hipStream_t stream) {
    const float* x = (const float*)d_in[0];   // [1024, 1024]
    const float* T = (const float*)d_in[1];   // [1024, 500]
    float* out = (float*)d_out;               // [1024, 1124]
    float* mt = (float*)d_ws;                 // [500][1024] f32, LOG2E-scaled (2MB)
    short* xb = (short*)((char*)d_ws + (size_t)CCOLS * B_SZ * sizeof(float)); // 2MB

    const size_t need = (size_t)CCOLS * B_SZ * sizeof(float)
                      + (size_t)2048 * 512 * sizeof(short);   // 4MB

    init_kernel<<<dim3(B_SZ), 256, 0, stream>>>(x, out);
    if (ws_size >= need) {
        stage_xb_kernel<<<dim3(512), 256, 0, stream>>>(x, xb);
        gemm_frag_kernel<<<dim3(512), 256, 0, stream>>>(T, xb, mt);
    } else {
        gemm_block_kernel<<<dim3(16, 32), 512, 0, stream>>>(x, T, mt);
    }
    pair_kernel<<<dim3(B_SZ / 64, NKER), 256, 0, stream>>>(mt, out);
}